// Round 9
// baseline (678.177 us; speedup 1.0000x reference)
//
#include <hip/hip_runtime.h>

typedef _Float16 f16;
typedef _Float16 f16x8 __attribute__((ext_vector_type(8)));
typedef float f32x4 __attribute__((ext_vector_type(4)));

// address_space(1) = global: forces global_load_* (vmcnt-only) instead of
// flat_load_* (which counts in BOTH vmcnt and lgkmcnt and gets drained by
// every lgkm wait — the r2 serializer).
typedef __attribute__((address_space(1))) const f16 gf16;
typedef __attribute__((address_space(1))) const f16x8 gf16x8;

#define N_TOT   8192
#define L_STEPS 32
#define H_DIM   256
#define OUT_DIM 128
#define BN      32
#define NBLK    256
#define THREADS 512

// workspace layout (bytes):
//   Wpack : 262144 f16 = 524288 B @ 0        (W_hh in B-frag order)
//   fcpack:  32768 f16 =  65536 B @ 524288   (fc_w in B-frag order)
//   bsum  :   1024 f32 =   4096 B @ 589824   (b_ih + b_hh)
#define WPACK_OFF  0
#define FCPACK_OFF 524288
#define BSUM_OFF   589824

__global__ __launch_bounds__(256) void prep_kernel(
    const float* __restrict__ W_hh, const float* __restrict__ fc_w,
    const float* __restrict__ b_ih, const float* __restrict__ b_hh,
    f16* __restrict__ Wpack, f16* __restrict__ fcpack, float* __restrict__ bsum)
{
    int p = blockIdx.x * blockDim.x + threadIdx.x;
    if (p < 262144) {
        // Wpack[((kb*64 + T)*64 + lane)*8 + e] = W_hh[g][k]
        // g = 16*T + (lane&15), k = 32*kb + 8*(lane>>4) + e
        int e = p & 7, lane = (p >> 3) & 63, T = (p >> 9) & 63, kb = p >> 15;
        int g = 16 * T + (lane & 15);
        int k = 32 * kb + 8 * (lane >> 4) + e;
        Wpack[p] = (f16)W_hh[g * 256 + k];
    } else if (p < 262144 + 32768) {
        int p2 = p - 262144;
        // fcpack[((kb*8 + ot)*64 + lane)*8 + e] = fc_w[o][k]
        int e = p2 & 7, lane = (p2 >> 3) & 63, ot = (p2 >> 9) & 7, kb = p2 >> 12;
        int o = 16 * ot + (lane & 15);
        int k = 32 * kb + 8 * (lane >> 4) + e;
        fcpack[p2] = (f16)fc_w[o * 256 + k];
    } else if (p < 262144 + 32768 + 1024) {
        int g = p - 262144 - 32768;
        bsum[g] = b_ih[g] + b_hh[g];
    }
}

__device__ __forceinline__ float sigmoid_(float x) {
    return 1.0f / (1.0f + __expf(-x));
}
__device__ __forceinline__ float tanh_(float x) {
    float t = __expf(-2.0f * x);
    return (1.0f - t) / (1.0f + t);
}

// LDS-only barrier: ds ops complete (lgkmcnt), but global weight loads and
// output stores stay IN FLIGHT across it.
__device__ __forceinline__ void lds_barrier() {
    asm volatile("s_waitcnt lgkmcnt(0)" ::: "memory");
    __builtin_amdgcn_s_barrier();
    asm volatile("" ::: "memory");
}

// 256 blocks x 512 threads (8 waves, 2 waves/SIMD, 1 block/CU).
// THIS REV = r3 (best: 363 us, FETCH 9.5 MB) + EXACTLY ONE change:
// barrier B removed via obuf double-buffering. Per step (ONE barrier):
//   [x-proj] [8 gate phases: ds_read a0/a1 -> 16 MFMA + depth-3 weight
//   refill (r3's exact schedule)] [elementwise -> hp[buf^1]] [lds_barrier]
//   [coop whole-line store of out[:, l-1, :] from obuf[(l-1)&1]]
//   [fc(hs[l]) -> obuf[l&1]]
// Hazard audit: obuf write(l) -> read(l+1) ordered by barrier_{l+1};
// read(l+1) -> write(l+2) ordered by barrier_{l+2}; h_new by barrier_l.
// r4 lesson: direct per-lane out stores -> partial-line RMW at TCC (823 MB
// fetch). obuf staging makes whole-line writes; never remove it.
// r5-r8 lesson: fused fc / saddr / LDS-const rewrites all perturbed regalloc
// into scratch traffic (FETCH 62-198 MB) and lost to r3. Single-variable
// changes only; FETCH is the guard metric.
__global__ __launch_bounds__(THREADS, 2) void lstm_kernel(
    const float* __restrict__ x, const float* __restrict__ W_ih,
    const f16* __restrict__ Wpack, const float* __restrict__ bsum,
    const f16* __restrict__ fcpack, const float* __restrict__ fc_b,
    float* __restrict__ out)
{
    __shared__ __align__(16) f16 hp[2][8192];             // h in A-frag order, dbuf
    __shared__ __align__(16) float obuf[2][BN * OUT_DIM]; // fc out staging, dbuf 32 KB

    const int tid  = threadIdx.x;
    const int wave = tid >> 6;
    const int lane = tid & 63;
    const int l15  = lane & 15;
    const int lq   = lane >> 4;
    const int n0   = blockIdx.x * BN;
    const int kb0  = (blockIdx.x >> 3) & 7;   // L2 de-hotspot rotation

    // ---- resident fc B-frags (8 KB/wave -> 32 VGPR) ----
    f16x8 fcw[8];
#pragma unroll
    for (int kb = 0; kb < 8; ++kb)
        fcw[kb] = *(const f16x8*)&fcpack[((kb * 8 + wave) * 64 + lane) * 8];

    // h(t=0) = 0
    for (int i = tid; i < 8192; i += THREADS) hp[0][i] = (f16)0.0f;

    // per-lane x-projection constants: g = 256*q + 16*(wave + 8*ti) + l15
    float wih0[2][4], wih1[2][4], bsv[2][4];
#pragma unroll
    for (int ti = 0; ti < 2; ++ti)
#pragma unroll
        for (int q = 0; q < 4; ++q) {
            int g = 256 * q + 16 * (wave + 8 * ti) + l15;
            wih0[ti][q] = W_ih[g * 2 + 0];
            wih1[ti][q] = W_ih[g * 2 + 1];
            bsv[ti][q]  = bsum[g];
        }
    const float fcbv = fc_b[16 * wave + l15];
    const int   ocol = 16 * wave + l15;

    float c[2][2][4];
#pragma unroll
    for (int ti = 0; ti < 2; ++ti)
#pragma unroll
        for (int mt = 0; mt < 2; ++mt)
#pragma unroll
            for (int r = 0; r < 4; ++r) c[ti][mt][r] = 0.0f;

    // weight stream base: f16 index = kb*32768 + q*8192 + ti*4096 + wave*512 + lane*8
    unsigned long long wb_u =
        (unsigned long long)(uintptr_t)(Wpack + wave * 512 + lane * 8);

    // prologue: phase 0 (kb0) -> slot 0, phase 1 (kb0+1) -> slot 1
    f16x8 wbuf[3][2][4];  // [slot][ti][q] — slot index always compile-time
    {
        gf16* wb = (gf16*)(uintptr_t)wb_u;
        int kbA = kb0, kbB = (kb0 + 1) & 7;
#pragma unroll
        for (int ti = 0; ti < 2; ++ti)
#pragma unroll
            for (int q = 0; q < 4; ++q) {
                wbuf[0][ti][q] = *(const gf16x8*)&wb[kbA * 32768 + q * 8192 + ti * 4096];
                wbuf[1][ti][q] = *(const gf16x8*)&wb[kbB * 32768 + q * 8192 + ti * 4096];
            }
    }

    // prefetch x for l=0
    float2 xc[2][4];
#pragma unroll
    for (int mt = 0; mt < 2; ++mt)
#pragma unroll
        for (int r = 0; r < 4; ++r) {
            int n = n0 + 16 * mt + 4 * lq + r;
            xc[mt][r] = *(const float2*)&x[(n * L_STEPS + 0) * 2];
        }

    __syncthreads();  // one-time full sync (h init visible); drains prologue too

    int buf = 0;
#pragma unroll 1
    for (int l = 0; l < L_STEPS; ++l) {
        // Defeat LICM: fresh weight base each step so the (l-invariant)
        // B-frag loads cannot be hoisted out of the l-loop (-> 256-VGPR
        // live set -> scratch spill, the r0 bug).
        asm volatile("" : "+v"(wb_u));
        gf16* wb = (gf16*)(uintptr_t)wb_u;

        // ---- accumulator init = x-projection (fp32 exact) ----
        f32x4 acc[2][2][4];  // [ti][mt][q]
#pragma unroll
        for (int mt = 0; mt < 2; ++mt)
#pragma unroll
            for (int r = 0; r < 4; ++r) {
#pragma unroll
                for (int ti = 0; ti < 2; ++ti)
#pragma unroll
                    for (int q = 0; q < 4; ++q)
                        acc[ti][mt][q][r] = bsv[ti][q] + xc[mt][r].x * wih0[ti][q]
                                                       + xc[mt][r].y * wih1[ti][q];
            }

        // software-prefetch x for l+1 (L1 is thrashed by the weight stream)
        float2 xn[2][4];
        if (l + 1 < L_STEPS) {
#pragma unroll
            for (int mt = 0; mt < 2; ++mt)
#pragma unroll
                for (int r = 0; r < 4; ++r) {
                    int n = n0 + 16 * mt + 4 * lq + r;
                    xn[mt][r] = *(const float2*)&x[(n * L_STEPS + l + 1) * 2];
                }
        }

        // ---- gates += h @ W_hh^T (B streamed from L2, A from LDS) ----
        // r3's exact depth-3 schedule: phase p consumes slot p%3; p<6 loads
        // slot (p+2)%3 with kb=(p+2+kb0)&7; p=6,7 prefetch next step's
        // phases 0,1 (those loads cross the elementwise window + barrier).
#pragma unroll
        for (int p = 0; p < 8; ++p) {
            const int sc = p % 3;              // slot consumed (compile-time)
            const int sl = (p + 2) % 3;        // slot loaded   (compile-time)
            const int kb_c = (p + kb0) & 7;    // kb consumed this phase

            if (p < 6) {
                const int kb_n = (p + 2 + kb0) & 7;
#pragma unroll
                for (int ti = 0; ti < 2; ++ti)
#pragma unroll
                    for (int q = 0; q < 4; ++q)
                        wbuf[sl][ti][q] =
                            *(const gf16x8*)&wb[kb_n * 32768 + q * 8192 + ti * 4096];
            }

            f16x8 a0 = *(const f16x8*)&hp[buf][((kb_c * 2 + 0) * 64 + lane) * 8];
            f16x8 a1 = *(const f16x8*)&hp[buf][((kb_c * 2 + 1) * 64 + lane) * 8];
#pragma unroll
            for (int ti = 0; ti < 2; ++ti)
#pragma unroll
                for (int q = 0; q < 4; ++q) {
                    acc[ti][0][q] = __builtin_amdgcn_mfma_f32_16x16x32_f16(
                        a0, wbuf[sc][ti][q], acc[ti][0][q], 0, 0, 0);
                    acc[ti][1][q] = __builtin_amdgcn_mfma_f32_16x16x32_f16(
                        a1, wbuf[sc][ti][q], acc[ti][1][q], 0, 0, 0);
                }

            // cross-step prefetch: next step's phases 0,1 into slots 0,1
            // (issued AFTER this phase's MFMAs consumed those slots)
            if (p == 6) {
                const int kb_n = kb0;
#pragma unroll
                for (int ti = 0; ti < 2; ++ti)
#pragma unroll
                    for (int q = 0; q < 4; ++q)
                        wbuf[0][ti][q] =
                            *(const gf16x8*)&wb[kb_n * 32768 + q * 8192 + ti * 4096];
            }
            if (p == 7) {
                const int kb_n = (kb0 + 1) & 7;
#pragma unroll
                for (int ti = 0; ti < 2; ++ti)
#pragma unroll
                    for (int q = 0; q < 4; ++q)
                        wbuf[1][ti][q] =
                            *(const gf16x8*)&wb[kb_n * 32768 + q * 8192 + ti * 4096];
            }
        }

        // ---- elementwise LSTM update (all 4 gates in-register per lane) ----
#pragma unroll
        for (int ti = 0; ti < 2; ++ti) {
            int j   = 16 * (wave + 8 * ti) + l15;
            int kbj = j >> 5, qk = (j >> 3) & 3, e = j & 7;
#pragma unroll
            for (int mt = 0; mt < 2; ++mt)
#pragma unroll
                for (int r = 0; r < 4; ++r) {
                    float gi = acc[ti][mt][0][r];
                    float gf = acc[ti][mt][1][r];
                    float gg = acc[ti][mt][2][r];
                    float go = acc[ti][mt][3][r];
                    float cn = sigmoid_(gf) * c[ti][mt][r] + sigmoid_(gi) * tanh_(gg);
                    c[ti][mt][r] = cn;
                    float hv = sigmoid_(go) * tanh_(cn);
                    int laneA = (4 * lq + r) | (qk << 4);
                    hp[buf ^ 1][((kbj * 2 + mt) * 64 + laneA) * 8 + e] = (f16)hv;
                }
        }
        lds_barrier();  // h_new + obuf[(l-1)&1] visible; prefetch in flight

        // ---- cooperative whole-line store of out[:, l-1, :] (deferred) ----
        if (l > 0) {
            const int row = tid >> 4;
            const int gl  = ((n0 + row) * L_STEPS + (l - 1)) * OUT_DIM;
#pragma unroll
            for (int half = 0; half < 2; ++half) {
                int col = (tid & 15) * 4 + half * 64;
                f32x4 v = *(const f32x4*)&obuf[(l - 1) & 1][row * OUT_DIM + col];
                *(f32x4*)&out[gl + col] = v;
            }
        }

        // ---- fc(hs[l]) -> obuf[l&1] (read by NEXT step's coop store) ----
        {
            f32x4 facc0 = {fcbv, fcbv, fcbv, fcbv};
            f32x4 facc1 = facc0;
#pragma unroll
            for (int kb = 0; kb < 8; ++kb) {
                f16x8 a0 = *(const f16x8*)&hp[buf ^ 1][((kb * 2 + 0) * 64 + lane) * 8];
                f16x8 a1 = *(const f16x8*)&hp[buf ^ 1][((kb * 2 + 1) * 64 + lane) * 8];
                facc0 = __builtin_amdgcn_mfma_f32_16x16x32_f16(a0, fcw[kb], facc0, 0, 0, 0);
                facc1 = __builtin_amdgcn_mfma_f32_16x16x32_f16(a1, fcw[kb], facc1, 0, 0, 0);
            }
#pragma unroll
            for (int r = 0; r < 4; ++r) {
                obuf[l & 1][(4 * lq + r) * OUT_DIM + ocol]      = facc0[r];
                obuf[l & 1][(16 + 4 * lq + r) * OUT_DIM + ocol] = facc1[r];
            }
        }

#pragma unroll
        for (int mt = 0; mt < 2; ++mt)
#pragma unroll
            for (int r = 0; r < 4; ++r) xc[mt][r] = xn[mt][r];
        buf ^= 1;
    }

    // ---- epilogue: store out[:, 31, :] from obuf[31&1 = 1] ----
    __syncthreads();
    {
        const int row = tid >> 4;
        const int gl  = ((n0 + row) * L_STEPS + 31) * OUT_DIM;
#pragma unroll
        for (int half = 0; half < 2; ++half) {
            int col = (tid & 15) * 4 + half * 64;
            f32x4 v = *(const f32x4*)&obuf[1][row * OUT_DIM + col];
            *(f32x4*)&out[gl + col] = v;
        }
    }
}

extern "C" void kernel_launch(void* const* d_in, const int* in_sizes, int n_in,
                              void* d_out, int out_size, void* d_ws, size_t ws_size,
                              hipStream_t stream) {
    const float* x    = (const float*)d_in[0];
    const float* W_ih = (const float*)d_in[1];
    const float* W_hh = (const float*)d_in[2];
    const float* b_ih = (const float*)d_in[3];
    const float* b_hh = (const float*)d_in[4];
    const float* fc_w = (const float*)d_in[5];
    const float* fc_b = (const float*)d_in[6];
    float* out = (float*)d_out;

    char* ws = (char*)d_ws;
    f16*   Wpack  = (f16*)(ws + WPACK_OFF);
    f16*   fcpack = (f16*)(ws + FCPACK_OFF);
    float* bsum   = (float*)(ws + BSUM_OFF);

    const int prep_elems = 262144 + 32768 + 1024;
    prep_kernel<<<(prep_elems + 255) / 256, 256, 0, stream>>>(
        W_hh, fc_w, b_ih, b_hh, Wpack, fcpack, bsum);

    lstm_kernel<<<NBLK, THREADS, 0, stream>>>(
        x, W_ih, Wpack, bsum, fcpack, fc_b, out);
}